// Round 4
// baseline (306.973 us; speedup 1.0000x reference)
//
#include <hip/hip_runtime.h>

#define B_ 2
#define H_ 16
#define S_ 2048
#define D_ 64

typedef __attribute__((ext_vector_type(8))) _Float16 half8;
typedef __attribute__((ext_vector_type(2))) __fp16 fp16x2;
typedef __attribute__((ext_vector_type(16))) float f32x16;

constexpr int QW  = 32;        // q rows per wave (MFMA N)
constexpr int NW  = 4;         // waves per block
constexpr int QB  = QW * NW;   // 128 q rows per block
constexpr int KVB = 32;        // kv rows per tile

__global__ __launch_bounds__(256, 2)
void fattn(const float* __restrict__ Qg, const float* __restrict__ Kg,
           const float* __restrict__ Vg, const float* __restrict__ Mg,
           float* __restrict__ Og)
{
    const int tid  = threadIdx.x;
    const int lane = tid & 63;
    const int lo32 = lane & 31;
    const int hi   = lane >> 5;
    const int wv   = tid >> 6;

    const int qblk = blockIdx.x;       // 0..15
    const int bh   = blockIdx.y;       // 0..31
    const int b    = bh >> 4;          // /H

    const float* Qp = Qg + (size_t)bh * S_ * D_;
    const float* Kp = Kg + (size_t)bh * S_ * D_;
    const float* Vp = Vg + (size_t)bh * S_ * D_;
    const float* Mp = Mg + (size_t)b  * S_ * S_;
    float*       Op = Og + (size_t)bh * S_ * D_;

    __shared__ __align__(16) _Float16 Khi[KVB * D_];
    __shared__ __align__(16) _Float16 Klo[KVB * D_];
    __shared__ __align__(16) _Float16 VThi[D_ * KVB];
    __shared__ __align__(16) _Float16 VTlo[D_ * KVB];

    const int qloc = qblk * QB + wv * QW + lo32;   // this lane's q row (MFMA col)

    // ---- Q fragments (B-operand), hi/lo split. frag f covers d = f*16 + hi*8 + j
    half8 Qhi[4], Qlo[4];
    #pragma unroll
    for (int f = 0; f < 4; ++f) {
        const float* src = Qp + (size_t)qloc * D_ + f * 16 + hi * 8;
        float4 a = *(const float4*)src;
        float4 c = *(const float4*)(src + 4);
        float v8[8] = {a.x, a.y, a.z, a.w, c.x, c.y, c.z, c.w};
        half8 hh, hl;
        #pragma unroll
        for (int j = 0; j < 8; ++j) {
            _Float16 h = (_Float16)v8[j];
            hh[j] = h;
            hl[j] = (_Float16)(v8[j] - (float)h);
        }
        Qhi[f] = hh; Qlo[f] = hl;
    }

    f32x16 acc0, acc1;                 // O^T accumulators (d 0..31 / 32..63)
    #pragma unroll
    for (int i = 0; i < 16; ++i) { acc0[i] = 0.f; acc1[i] = 0.f; }
    float mrun = -1e30f, lrun = 0.f;

    const float kScL2 = 0.125f * 1.44269504088896340736f;   // scale * log2(e)
    const float kL2E  = 1.44269504088896340736f;

    const int sr = tid >> 3;   // staging row 0..31
    const int sc = tid & 7;    // staging chunk 0..7

    for (int kv = 0; kv < S_; kv += KVB) {
        __syncthreads();
        // ---------- stage K tile [KVB][64] (chunk-XOR swizzled rows, 128B/row)
        {
            const float* src = Kp + (size_t)(kv + sr) * D_ + sc * 8;
            float4 a = *(const float4*)src;
            float4 c = *(const float4*)(src + 4);
            float v8[8] = {a.x, a.y, a.z, a.w, c.x, c.y, c.z, c.w};
            half8 hh, hl;
            #pragma unroll
            for (int j = 0; j < 8; ++j) {
                _Float16 h = (_Float16)v8[j];
                hh[j] = h;
                hl[j] = (_Float16)(v8[j] - (float)h);
            }
            const int cs = sc ^ (sr & 7);
            *(half8*)&Khi[sr * 64 + cs * 8] = hh;
            *(half8*)&Klo[sr * 64 + cs * 8] = hl;
        }
        // ---------- stage V^T tile [64][KVB] (chunk-XOR swizzled, 64B/row)
        {
            const float* src = Vp + (size_t)(kv + sr) * D_ + sc * 8;
            float4 a = *(const float4*)src;
            float4 c = *(const float4*)(src + 4);
            float v8[8] = {a.x, a.y, a.z, a.w, c.x, c.y, c.z, c.w};
            #pragma unroll
            for (int j = 0; j < 8; ++j) {
                const int d = sc * 8 + j;
                const int cc = (sr >> 3) ^ ((d >> 1) & 3);
                _Float16 h = (_Float16)v8[j];
                VThi[d * 32 + cc * 8 + (sr & 7)] = h;
                VTlo[d * 32 + cc * 8 + (sr & 7)] = (_Float16)(v8[j] - (float)h);
            }
        }
        __syncthreads();

        // ---------- S^T = K · Q^T  (3-term hi/lo split)
        f32x16 s;
        #pragma unroll
        for (int i = 0; i < 16; ++i) s[i] = 0.f;
        #pragma unroll
        for (int f = 0; f < 4; ++f) {
            const int cs = (2 * f + hi) ^ (lo32 & 7);
            half8 ah = *(const half8*)&Khi[lo32 * 64 + cs * 8];
            half8 al = *(const half8*)&Klo[lo32 * 64 + cs * 8];
            s = __builtin_amdgcn_mfma_f32_32x32x16_f16(ah, Qhi[f], s, 0, 0, 0);
            s = __builtin_amdgcn_mfma_f32_32x32x16_f16(al, Qhi[f], s, 0, 0, 0);
            s = __builtin_amdgcn_mfma_f32_32x32x16_f16(ah, Qlo[f], s, 0, 0, 0);
        }

        // ---------- scale + mask (base-2 log domain). lane row kk = (r&3)+8*(r>>2)+4*hi
        const float* mrow = Mp + (size_t)qloc * S_ + kv;
        float p[16];
        #pragma unroll
        for (int g = 0; g < 4; ++g) {
            float4 mv = *(const float4*)(mrow + 8 * g + 4 * hi);
            p[4*g+0] = fmaf(s[4*g+0], kScL2, mv.x * kL2E);
            p[4*g+1] = fmaf(s[4*g+1], kScL2, mv.y * kL2E);
            p[4*g+2] = fmaf(s[4*g+2], kScL2, mv.z * kL2E);
            p[4*g+3] = fmaf(s[4*g+3], kScL2, mv.w * kL2E);
        }

        // ---------- online softmax (lane-local + 1 partner shuffle)
        float mt = p[0];
        #pragma unroll
        for (int r = 1; r < 16; ++r) mt = fmaxf(mt, p[r]);
        mt = fmaxf(mt, __shfl_xor(mt, 32));
        const float mnew = fmaxf(mrun, mt);
        const float corr = __builtin_amdgcn_exp2f(mrun - mnew);
        float ps = 0.f;
        #pragma unroll
        for (int r = 0; r < 16; ++r) {
            p[r] = __builtin_amdgcn_exp2f(p[r] - mnew);
            ps += p[r];
        }
        ps += __shfl_xor(ps, 32);
        lrun = lrun * corr + ps;
        mrun = mnew;
        #pragma unroll
        for (int i = 0; i < 16; ++i) { acc0[i] *= corr; acc1[i] *= corr; }

        // ---------- pack P to f16 and build B-operand frags (kk = ks*16 + hi*8 + j)
        int dw[8], px[8];
        #pragma unroll
        for (int g = 0; g < 4; ++g) {
            union { fp16x2 h; int i; } u0, u1;
            u0.h = __builtin_amdgcn_cvt_pkrtz(p[4*g+0], p[4*g+1]);
            u1.h = __builtin_amdgcn_cvt_pkrtz(p[4*g+2], p[4*g+3]);
            dw[2*g]   = u0.i;
            dw[2*g+1] = u1.i;
        }
        #pragma unroll
        for (int i = 0; i < 8; ++i) px[i] = __shfl_xor(dw[i], 32);

        half8 Pf[2];
        #pragma unroll
        for (int ks = 0; ks < 2; ++ks) {
            union { int i[4]; half8 h; } f;
            f.i[0] = hi ? px[4*ks+2] : dw[4*ks+0];
            f.i[1] = hi ? px[4*ks+3] : dw[4*ks+1];
            f.i[2] = hi ? dw[4*ks+2] : px[4*ks+0];
            f.i[3] = hi ? dw[4*ks+3] : px[4*ks+1];
            Pf[ks] = f.h;
        }

        // ---------- O^T += V^T · P   (V hi/lo split)
        #pragma unroll
        for (int ks = 0; ks < 2; ++ks) {
            const int cc = (2 * ks + hi) ^ ((lo32 >> 1) & 3);
            half8 vh0 = *(const half8*)&VThi[(lo32)      * 32 + cc * 8];
            half8 vl0 = *(const half8*)&VTlo[(lo32)      * 32 + cc * 8];
            half8 vh1 = *(const half8*)&VThi[(32 + lo32) * 32 + cc * 8];
            half8 vl1 = *(const half8*)&VTlo[(32 + lo32) * 32 + cc * 8];
            acc0 = __builtin_amdgcn_mfma_f32_32x32x16_f16(vh0, Pf[ks], acc0, 0, 0, 0);
            acc0 = __builtin_amdgcn_mfma_f32_32x32x16_f16(vl0, Pf[ks], acc0, 0, 0, 0);
            acc1 = __builtin_amdgcn_mfma_f32_32x32x16_f16(vh1, Pf[ks], acc1, 0, 0, 0);
            acc1 = __builtin_amdgcn_mfma_f32_32x32x16_f16(vl1, Pf[ks], acc1, 0, 0, 0);
        }
    }

    // ---------- epilogue: O[q][d] = acc^T / l
    const float inv = 1.0f / lrun;
    #pragma unroll
    for (int r = 0; r < 16; ++r) {
        const int drow = (r & 3) + 8 * (r >> 2) + 4 * hi;
        Op[(size_t)qloc * D_ + drow]      = acc0[r] * inv;
        Op[(size_t)qloc * D_ + 32 + drow] = acc1[r] * inv;
    }
}

extern "C" void kernel_launch(void* const* d_in, const int* in_sizes, int n_in,
                              void* d_out, int out_size, void* d_ws, size_t ws_size,
                              hipStream_t stream)
{
    (void)in_sizes; (void)n_in; (void)out_size; (void)d_ws; (void)ws_size;
    const float* Q = (const float*)d_in[0];
    const float* K = (const float*)d_in[1];
    const float* V = (const float*)d_in[2];
    const float* M = (const float*)d_in[3];
    float* O = (float*)d_out;

    dim3 grid(S_ / QB, B_ * H_);
    fattn<<<grid, 256, 0, stream>>>(Q, K, V, M, O);
}

// Round 8
// 240.972 us; speedup vs baseline: 1.2739x; 1.2739x over previous
//
#include <hip/hip_runtime.h>

#define B_ 2
#define H_ 16
#define S_ 2048
#define D_ 64

typedef __attribute__((ext_vector_type(8))) _Float16 half8;
typedef __attribute__((ext_vector_type(2))) __fp16 fp16x2;
typedef __attribute__((ext_vector_type(16))) float f32x16;

constexpr int QW  = 32;        // q rows per wave (MFMA N)
constexpr int NW  = 2;         // waves per block
constexpr int QB  = QW * NW;   // 64 q rows per block
constexpr int KVB = 32;        // kv rows per tile
constexpr int NIT = S_ / KVB;  // 64 tiles

__global__ __launch_bounds__(128, 2)
void fattn(const float* __restrict__ Qg, const float* __restrict__ Kg,
           const float* __restrict__ Vg, const float* __restrict__ Mg,
           float* __restrict__ Og)
{
    const int tid  = threadIdx.x;
    const int lo32 = tid & 31;
    const int hi   = (tid >> 5) & 1;
    const int wv   = tid >> 6;

    const int qblk = blockIdx.x;       // 0..31
    const int bh   = blockIdx.y;       // 0..31
    const int b    = bh >> 4;          // /H

    const float* Qp = Qg + (size_t)bh * S_ * D_;
    const float* Kp = Kg + (size_t)bh * S_ * D_;
    const float* Vp = Vg + (size_t)bh * S_ * D_;
    const float* Mp = Mg + (size_t)b  * S_ * S_;
    float*       Op = Og + (size_t)bh * S_ * D_;

    // double-buffered tiles: 4 arrays x 2 bufs x 2048 halves x 2B = 32 KB
    __shared__ __align__(16) _Float16 Khi[2][KVB * D_];
    __shared__ __align__(16) _Float16 Klo[2][KVB * D_];
    __shared__ __align__(16) _Float16 VThi[2][D_ * KVB];
    __shared__ __align__(16) _Float16 VTlo[2][D_ * KVB];

    const int qloc = qblk * QB + wv * QW + lo32;   // this lane's q row (MFMA col)

    // staging assignments
    const int ksr = tid >> 2;      // 0..31  K row
    const int ksc = tid & 3;       // 0..3   K 16-float chunk
    const int vd  = tid & 63;      // 0..63  V column (d)
    const int vw  = tid >> 6;      // 0..1   V kv-half

    // ---- Q fragments (B-operand), hi/lo split. frag f covers d = f*16 + hi*8 + j
    half8 Qhi[4], Qlo[4];
    #pragma unroll
    for (int f = 0; f < 4; ++f) {
        const float* src = Qp + (size_t)qloc * D_ + f * 16 + hi * 8;
        float4 a = *(const float4*)src;
        float4 c = *(const float4*)(src + 4);
        float v8[8] = {a.x, a.y, a.z, a.w, c.x, c.y, c.z, c.w};
        half8 hh, hl;
        #pragma unroll
        for (int j = 0; j < 8; ++j) {
            _Float16 h = (_Float16)v8[j];
            hh[j] = h;
            hl[j] = (_Float16)(v8[j] - (float)h);
        }
        Qhi[f] = hh; Qlo[f] = hl;
    }

    f32x16 acc0, acc1;                 // O^T accumulators (d 0..31 / 32..63)
    #pragma unroll
    for (int i = 0; i < 16; ++i) { acc0[i] = 0.f; acc1[i] = 0.f; }
    float mrun = -1e30f, lrun = 0.f;

    const float kScL2 = 0.125f * 1.44269504088896340736f;   // scale * log2(e)
    const float kL2E  = 1.44269504088896340736f;

    // prefetch registers (T14 async-stage: issue early, convert+write late)
    float4 kr[4];
    float  vr[16];
    float4 mcur[4], mnxt[4];

    auto stage_load = [&](int kv) {
        const float* ks = Kp + (size_t)(kv + ksr) * D_ + ksc * 16;
        #pragma unroll
        for (int i = 0; i < 4; ++i) kr[i] = *(const float4*)(ks + 4 * i);
        const float* vs = Vp + (size_t)(kv + vw * 16) * D_ + vd;
        #pragma unroll
        for (int r = 0; r < 16; ++r) vr[r] = vs[(size_t)r * D_];
    };
    auto stage_write = [&](int bf) {
        // K tile [KVB][64], half8 rows, chunk-XOR swizzle (8 lanes/bank-quad = min)
        #pragma unroll
        for (int u = 0; u < 2; ++u) {
            float e[8] = {kr[2*u].x, kr[2*u].y, kr[2*u].z, kr[2*u].w,
                          kr[2*u+1].x, kr[2*u+1].y, kr[2*u+1].z, kr[2*u+1].w};
            half8 hh, hl;
            #pragma unroll
            for (int j = 0; j < 8; ++j) {
                _Float16 h = (_Float16)e[j];
                hh[j] = h;
                hl[j] = (_Float16)(e[j] - (float)h);
            }
            const int cs = (ksc * 2 + u) ^ (ksr & 7);
            *(half8*)&Khi[bf][ksr * 64 + cs * 8] = hh;
            *(half8*)&Klo[bf][ksr * 64 + cs * 8] = hl;
        }
        // V^T tile [64][KVB]: lane owns column d -> contiguous half8 writes,
        // chunk swizzle c = logical ^ (d&3) ^ ((d>>2)&3) spreads bank quads
        #pragma unroll
        for (int u = 0; u < 2; ++u) {
            half8 hh, hl;
            #pragma unroll
            for (int j = 0; j < 8; ++j) {
                float x = vr[8*u + j];
                _Float16 h = (_Float16)x;
                hh[j] = h;
                hl[j] = (_Float16)(x - (float)h);
            }
            const int c = (vw * 2 + u) ^ (vd & 3) ^ ((vd >> 2) & 3);
            *(half8*)&VThi[bf][vd * 32 + c * 8] = hh;
            *(half8*)&VTlo[bf][vd * 32 + c * 8] = hl;
        }
    };
    auto mask_load = [&](int kv, float4* mv) {
        const float* mrow = Mp + (size_t)qloc * S_ + kv;
        #pragma unroll
        for (int g = 0; g < 4; ++g) mv[g] = *(const float4*)(mrow + 8 * g + 4 * hi);
    };

    // ---- prologue: stage tile 0, mask 0
    stage_load(0);
    stage_write(0);
    mask_load(0, mcur);
    __syncthreads();

    for (int t = 0; t < NIT; ++t) {
        const int bf = t & 1;
        if (t + 1 < NIT) {
            mask_load((t + 1) * KVB, mnxt);   // prefetch next mask row chunk
            stage_load((t + 1) * KVB);        // issue next K/V global loads
        }

        // ---------- S^T = K · Q^T  (3-term hi/lo split)
        f32x16 s;
        #pragma unroll
        for (int i = 0; i < 16; ++i) s[i] = 0.f;
        #pragma unroll
        for (int f = 0; f < 4; ++f) {
            const int cs = (2 * f + hi) ^ (lo32 & 7);
            half8 ah = *(const half8*)&Khi[bf][lo32 * 64 + cs * 8];
            half8 al = *(const half8*)&Klo[bf][lo32 * 64 + cs * 8];
            s = __builtin_amdgcn_mfma_f32_32x32x16_f16(ah, Qhi[f], s, 0, 0, 0);
            s = __builtin_amdgcn_mfma_f32_32x32x16_f16(al, Qhi[f], s, 0, 0, 0);
            s = __builtin_amdgcn_mfma_f32_32x32x16_f16(ah, Qlo[f], s, 0, 0, 0);
        }

        // ---------- scale + mask (base-2 log domain). lane row kk = (r&3)+8*(r>>2)+4*hi
        float p[16];
        #pragma unroll
        for (int g = 0; g < 4; ++g) {
            p[4*g+0] = fmaf(s[4*g+0], kScL2, mcur[g].x * kL2E);
            p[4*g+1] = fmaf(s[4*g+1], kScL2, mcur[g].y * kL2E);
            p[4*g+2] = fmaf(s[4*g+2], kScL2, mcur[g].z * kL2E);
            p[4*g+3] = fmaf(s[4*g+3], kScL2, mcur[g].w * kL2E);
        }

        // ---------- online softmax (lane-local + 1 partner shuffle)
        float mt = p[0];
        #pragma unroll
        for (int r = 1; r < 16; ++r) mt = fmaxf(mt, p[r]);
        mt = fmaxf(mt, __shfl_xor(mt, 32));
        const float mnew = fmaxf(mrun, mt);
        const float corr = __builtin_amdgcn_exp2f(mrun - mnew);
        float ps = 0.f;
        #pragma unroll
        for (int r = 0; r < 16; ++r) {
            p[r] = __builtin_amdgcn_exp2f(p[r] - mnew);
            ps += p[r];
        }
        ps += __shfl_xor(ps, 32);
        lrun = lrun * corr + ps;
        mrun = mnew;
        #pragma unroll
        for (int i = 0; i < 16; ++i) { acc0[i] *= corr; acc1[i] *= corr; }

        // ---------- pack P to f16 and build B-operand frags (kk = ks*16 + hi*8 + j)
        int dw[8], px[8];
        #pragma unroll
        for (int g = 0; g < 4; ++g) {
            union { fp16x2 h; int i; } u0, u1;
            u0.h = __builtin_amdgcn_cvt_pkrtz(p[4*g+0], p[4*g+1]);
            u1.h = __builtin_amdgcn_cvt_pkrtz(p[4*g+2], p[4*g+3]);
            dw[2*g]   = u0.i;
            dw[2*g+1] = u1.i;
        }
        #pragma unroll
        for (int i = 0; i < 8; ++i) px[i] = __shfl_xor(dw[i], 32);

        half8 Pf[2];
        #pragma unroll
        for (int ks = 0; ks < 2; ++ks) {
            union { int i[4]; half8 h; } f;
            f.i[0] = hi ? px[4*ks+2] : dw[4*ks+0];
            f.i[1] = hi ? px[4*ks+3] : dw[4*ks+1];
            f.i[2] = hi ? dw[4*ks+2] : px[4*ks+0];
            f.i[3] = hi ? dw[4*ks+3] : px[4*ks+1];
            Pf[ks] = f.h;
        }

        // ---------- O^T += V^T · P   (V hi/lo split)
        #pragma unroll
        for (int ks = 0; ks < 2; ++ks) {
            const int c0 = (2 * ks + hi) ^ (lo32 & 3) ^ ((lo32 >> 2) & 3);
            half8 vh0 = *(const half8*)&VThi[bf][lo32        * 32 + c0 * 8];
            half8 vl0 = *(const half8*)&VTlo[bf][lo32        * 32 + c0 * 8];
            half8 vh1 = *(const half8*)&VThi[bf][(32 + lo32) * 32 + c0 * 8];
            half8 vl1 = *(const half8*)&VTlo[bf][(32 + lo32) * 32 + c0 * 8];
            acc0 = __builtin_amdgcn_mfma_f32_32x32x16_f16(vh0, Pf[ks], acc0, 0, 0, 0);
            acc0 = __builtin_amdgcn_mfma_f32_32x32x16_f16(vl0, Pf[ks], acc0, 0, 0, 0);
            acc1 = __builtin_amdgcn_mfma_f32_32x32x16_f16(vh1, Pf[ks], acc1, 0, 0, 0);
            acc1 = __builtin_amdgcn_mfma_f32_32x32x16_f16(vl1, Pf[ks], acc1, 0, 0, 0);
        }

        // ---------- write next tile into the other buffer; single barrier per iter
        if (t + 1 < NIT) stage_write(bf ^ 1);
        #pragma unroll
        for (int g = 0; g < 4; ++g) mcur[g] = mnxt[g];
        __syncthreads();
    }

    // ---------- epilogue: O[q][d] = acc^T / l
    const float inv = 1.0f / lrun;
    #pragma unroll
    for (int r = 0; r < 16; ++r) {
        const int drow = (r & 3) + 8 * (r >> 2) + 4 * hi;
        Op[(size_t)qloc * D_ + drow]      = acc0[r] * inv;
        Op[(size_t)qloc * D_ + 32 + drow] = acc1[r] * inv;
    }
}

extern "C" void kernel_launch(void* const* d_in, const int* in_sizes, int n_in,
                              void* d_out, int out_size, void* d_ws, size_t ws_size,
                              hipStream_t stream)
{
    (void)in_sizes; (void)n_in; (void)out_size; (void)d_ws; (void)ws_size;
    const float* Q = (const float*)d_in[0];
    const float* K = (const float*)d_in[1];
    const float* V = (const float*)d_in[2];
    const float* M = (const float*)d_in[3];
    float* O = (float*)d_out;

    dim3 grid(S_ / QB, B_ * H_);
    fattn<<<grid, 128, 0, stream>>>(Q, K, V, M, O);
}

// Round 11
// 230.031 us; speedup vs baseline: 1.3345x; 1.0476x over previous
//
#include <hip/hip_runtime.h>

#define B_ 2
#define H_ 16
#define S_ 2048
#define D_ 64

typedef __attribute__((ext_vector_type(8))) _Float16 half8;
typedef __attribute__((ext_vector_type(2))) __fp16 fp16x2;
typedef __attribute__((ext_vector_type(16))) float f32x16;

constexpr int QW  = 32;        // q rows per wave (MFMA N)
constexpr int NW  = 2;         // waves per block
constexpr int QB  = QW * NW;   // 64 q rows per block
constexpr int KVB = 32;        // kv rows per tile
constexpr int NIT = S_ / KVB;  // 64 tiles

#define GLOBAL_AS(p) ((const __attribute__((address_space(1))) void*)(p))
#define LDS_AS(p)    ((__attribute__((address_space(3))) void*)(p))

// ---------------------------------------------------------------------------
// Pre-pass: split K,V into f16 hi/lo, transpose V, bake the LDS swizzle into
// the global layout so the attention kernel can global_load_lds linearly.
// Chunk layout per (bh, tile): 8192 halves = 16KB:
//   [0,2048)    Khi   [32 rows][64 cols], chunk cs = l ^ (r&7)
//   [2048,4096) Klo
//   [4096,6144) VThi  [64 d][32 k], chunk cw = c ^ (d&3) ^ ((d>>2)&3)
//   [6144,8192) VTlo
// ---------------------------------------------------------------------------
__global__ __launch_bounds__(256)
void presplit(const float* __restrict__ Kg, const float* __restrict__ Vg,
              _Float16* __restrict__ W)
{
    const int t   = blockIdx.x;    // kv tile 0..63
    const int bh  = blockIdx.y;    // 0..31
    const int tid = threadIdx.x;

    const float* Kp = Kg + (size_t)bh * S_ * D_ + (size_t)t * KVB * D_;
    const float* Vp = Vg + (size_t)bh * S_ * D_ + (size_t)t * KVB * D_;
    _Float16*    Wp = W + ((size_t)bh * NIT + t) * 8192;

    // ---- K: r = tid>>3 (row 0..31), l = tid&7 (8-col chunk)
    {
        const int r = tid >> 3, l = tid & 7;
        const float* src = Kp + r * D_ + l * 8;
        float4 a = *(const float4*)src;
        float4 c = *(const float4*)(src + 4);
        float e[8] = {a.x, a.y, a.z, a.w, c.x, c.y, c.z, c.w};
        half8 hh, hl;
        #pragma unroll
        for (int j = 0; j < 8; ++j) {
            _Float16 h = (_Float16)e[j];
            hh[j] = h;
            hl[j] = (_Float16)(e[j] - (float)h);
        }
        const int cs = l ^ (r & 7);
        *(half8*)&Wp[r * 64 + cs * 8]        = hh;
        *(half8*)&Wp[2048 + r * 64 + cs * 8] = hl;
    }
    // ---- V^T: d = tid&63 (column), c = tid>>6 (8-row chunk of k)
    {
        const int d = tid & 63, c = tid >> 6;
        float e[8];
        #pragma unroll
        for (int j = 0; j < 8; ++j) e[j] = Vp[(size_t)(c * 8 + j) * D_ + d];
        half8 hh, hl;
        #pragma unroll
        for (int j = 0; j < 8; ++j) {
            _Float16 h = (_Float16)e[j];
            hh[j] = h;
            hl[j] = (_Float16)(e[j] - (float)h);
        }
        const int cw = c ^ (d & 3) ^ ((d >> 2) & 3);
        *(half8*)&Wp[4096 + d * 32 + cw * 8] = hh;
        *(half8*)&Wp[6144 + d * 32 + cw * 8] = hl;
    }
}

// ---------------------------------------------------------------------------
// Fast attention kernel: pre-split K/V staged via global_load_lds (zero VALU)
// ---------------------------------------------------------------------------
__global__ __launch_bounds__(128, 2)
void fattn2(const float* __restrict__ Qg, const float* __restrict__ Mg,
            const _Float16* __restrict__ W, float* __restrict__ Og)
{
    const int tid  = threadIdx.x;
    const int lane = tid & 63;
    const int lo32 = tid & 31;
    const int hi   = (tid >> 5) & 1;
    const int wv   = tid >> 6;

    const int qblk = blockIdx.x;       // 0..31
    const int bh   = blockIdx.y;       // 0..31
    const int b    = bh >> 4;

    const float* Qp = Qg + (size_t)bh * S_ * D_;
    const float* Mp = Mg + (size_t)b  * S_ * S_;
    float*       Op = Og + (size_t)bh * S_ * D_;
    const _Float16* Wp = W + (size_t)bh * NIT * 8192;

    // one 16KB tile per buffer: [0,2048) Khi | Klo | VThi | VTlo
    __shared__ __align__(16) _Float16 TILE[2][8192];

    const int qloc = qblk * QB + wv * QW + lo32;

    // ---- Q fragments (B-operand), hi/lo split
    half8 Qhi[4], Qlo[4];
    #pragma unroll
    for (int f = 0; f < 4; ++f) {
        const float* src = Qp + (size_t)qloc * D_ + f * 16 + hi * 8;
        float4 a = *(const float4*)src;
        float4 c = *(const float4*)(src + 4);
        float v8[8] = {a.x, a.y, a.z, a.w, c.x, c.y, c.z, c.w};
        half8 hh, hl;
        #pragma unroll
        for (int j = 0; j < 8; ++j) {
            _Float16 h = (_Float16)v8[j];
            hh[j] = h;
            hl[j] = (_Float16)(v8[j] - (float)h);
        }
        Qhi[f] = hh; Qlo[f] = hl;
    }

    f32x16 acc0, acc1;
    #pragma unroll
    for (int i = 0; i < 16; ++i) { acc0[i] = 0.f; acc1[i] = 0.f; }
    float mrun = -1e30f, lrun = 0.f;

    const float kScL2 = 0.125f * 1.44269504088896340736f;
    const float kL2E  = 1.44269504088896340736f;

    float4 mcur[4], mnxt[4];

    // wave wv stages halves [wv*4096, wv*4096+4096): 8 x 1KB global_load_lds
    auto stage = [&](int bf, int t) {
        const _Float16* src = Wp + (size_t)t * 8192 + wv * 4096 + lane * 8;
        _Float16* dst = &TILE[bf][wv * 4096];
        #pragma unroll
        for (int c = 0; c < 8; ++c)
            __builtin_amdgcn_global_load_lds(GLOBAL_AS(src + c * 512),
                                             LDS_AS(dst + c * 512), 16, 0, 0);
    };
    auto mask_load = [&](int kv, float4* mv) {
        const float* mrow = Mp + (size_t)qloc * S_ + kv;
        #pragma unroll
        for (int g = 0; g < 4; ++g) mv[g] = *(const float4*)(mrow + 8 * g + 4 * hi);
    };

    stage(0, 0);
    mask_load(0, mcur);
    __syncthreads();

    for (int t = 0; t < NIT; ++t) {
        const int bf = t & 1;
        if (t + 1 < NIT) {
            mask_load((t + 1) * KVB, mnxt);
            stage(bf ^ 1, t + 1);         // prefetch; drained by end-of-iter barrier
        }

        // ---------- S^T = K · Q^T  (3-term hi/lo split)
        f32x16 s;
        #pragma unroll
        for (int i = 0; i < 16; ++i) s[i] = 0.f;
        #pragma unroll
        for (int f = 0; f < 4; ++f) {
            const int cs = (2 * f + hi) ^ (lo32 & 7);
            half8 ah = *(const half8*)&TILE[bf][lo32 * 64 + cs * 8];
            half8 al = *(const half8*)&TILE[bf][2048 + lo32 * 64 + cs * 8];
            s = __builtin_amdgcn_mfma_f32_32x32x16_f16(ah, Qhi[f], s, 0, 0, 0);
            s = __builtin_amdgcn_mfma_f32_32x32x16_f16(al, Qhi[f], s, 0, 0, 0);
            s = __builtin_amdgcn_mfma_f32_32x32x16_f16(ah, Qlo[f], s, 0, 0, 0);
        }

        // ---------- scale + mask (base-2 log domain)
        float p[16];
        #pragma unroll
        for (int g = 0; g < 4; ++g) {
            p[4*g+0] = fmaf(s[4*g+0], kScL2, mcur[g].x * kL2E);
            p[4*g+1] = fmaf(s[4*g+1], kScL2, mcur[g].y * kL2E);
            p[4*g+2] = fmaf(s[4*g+2], kScL2, mcur[g].z * kL2E);
            p[4*g+3] = fmaf(s[4*g+3], kScL2, mcur[g].w * kL2E);
        }

        // ---------- online softmax + T13 defer-max (P bounded by 2^8)
        float mt = p[0];
        #pragma unroll
        for (int r = 1; r < 16; ++r) mt = fmaxf(mt, p[r]);
        mt = fmaxf(mt, __shfl_xor(mt, 32));
        if (!__all(mt - mrun <= 8.0f)) {
            const float mnew = fmaxf(mrun, mt);
            const float corr = __builtin_amdgcn_exp2f(mrun - mnew);
            lrun *= corr;
            #pragma unroll
            for (int i = 0; i < 16; ++i) { acc0[i] *= corr; acc1[i] *= corr; }
            mrun = mnew;
        }
        float ps = 0.f;
        #pragma unroll
        for (int r = 0; r < 16; ++r) {
            p[r] = __builtin_amdgcn_exp2f(p[r] - mrun);
            ps += p[r];
        }
        ps += __shfl_xor(ps, 32);
        lrun += ps;

        // ---------- pack P to f16 and build B-operand frags
        int dw[8], px[8];
        #pragma unroll
        for (int g = 0; g < 4; ++g) {
            union { fp16x2 h; int i; } u0, u1;
            u0.h = __builtin_amdgcn_cvt_pkrtz(p[4*g+0], p[4*g+1]);
            u1.h = __builtin_amdgcn_cvt_pkrtz(p[4*g+2], p[4*g+3]);
            dw[2*g]   = u0.i;
            dw[2*g+1] = u1.i;
        }
        #pragma unroll
        for (int i = 0; i < 8; ++i) px[i] = __shfl_xor(dw[i], 32);

        half8 Pf[2];
        #pragma unroll
        for (int ks = 0; ks < 2; ++ks) {
            union { int i[4]; half8 h; } f;
            f.i[0] = hi ? px[4*ks+2] : dw[4*ks+0];
            f.i[1] = hi ? px[4*ks+3] : dw[4*ks+1];
            f.i[2] = hi ? dw[4*ks+2] : px[4*ks+0];
            f.i[3] = hi ? dw[4*ks+3] : px[4*ks+1];
            Pf[ks] = f.h;
        }

        // ---------- O^T += V^T · P   (V hi/lo split)
        #pragma unroll
        for (int ks = 0; ks < 2; ++ks) {
            const int c0 = (2 * ks + hi) ^ (lo32 & 3) ^ ((lo32 >> 2) & 3);
            half8 vh0 = *(const half8*)&TILE[bf][4096 + lo32        * 32 + c0 * 8];
            half8 vl0 = *(const half8*)&TILE[bf][6144 + lo32        * 32 + c0 * 8];
            half8 vh1 = *(const half8*)&TILE[bf][4096 + (32 + lo32) * 32 + c0 * 8];
            half8 vl1 = *(const half8*)&TILE[bf][6144 + (32 + lo32) * 32 + c0 * 8];
            acc0 = __builtin_amdgcn_mfma_f32_32x32x16_f16(vh0, Pf[ks], acc0, 0, 0, 0);
            acc0 = __builtin_amdgcn_mfma_f32_32x32x16_f16(vl0, Pf[ks], acc0, 0, 0, 0);
            acc1 = __builtin_amdgcn_mfma_f32_32x32x16_f16(vh1, Pf[ks], acc1, 0, 0, 0);
            acc1 = __builtin_amdgcn_mfma_f32_32x32x16_f16(vl1, Pf[ks], acc1, 0, 0, 0);
        }

        #pragma unroll
        for (int g = 0; g < 4; ++g) mcur[g] = mnxt[g];
        __syncthreads();   // drains prefetch vmcnt + flips buffers
    }

    const float inv = 1.0f / lrun;
    #pragma unroll
    for (int r = 0; r < 16; ++r) {
        const int drow = (r & 3) + 8 * (r >> 2) + 4 * hi;
        Op[(size_t)qloc * D_ + drow]      = acc0[r] * inv;
        Op[(size_t)qloc * D_ + 32 + drow] = acc1[r] * inv;
    }
}

// ---------------------------------------------------------------------------
// Fallback (R4 kernel, verified PASS @ ~170us): used when ws_size is too small
// ---------------------------------------------------------------------------
__global__ __launch_bounds__(128, 2)
void fattn(const float* __restrict__ Qg, const float* __restrict__ Kg,
           const float* __restrict__ Vg, const float* __restrict__ Mg,
           float* __restrict__ Og)
{
    const int tid  = threadIdx.x;
    const int lo32 = tid & 31;
    const int hi   = (tid >> 5) & 1;
    const int wv   = tid >> 6;

    const int qblk = blockIdx.x;
    const int bh   = blockIdx.y;
    const int b    = bh >> 4;

    const float* Qp = Qg + (size_t)bh * S_ * D_;
    const float* Kp = Kg + (size_t)bh * S_ * D_;
    const float* Vp = Vg + (size_t)bh * S_ * D_;
    const float* Mp = Mg + (size_t)b  * S_ * S_;
    float*       Op = Og + (size_t)bh * S_ * D_;

    __shared__ __align__(16) _Float16 Khi[2][KVB * D_];
    __shared__ __align__(16) _Float16 Klo[2][KVB * D_];
    __shared__ __align__(16) _Float16 VThi[2][D_ * KVB];
    __shared__ __align__(16) _Float16 VTlo[2][D_ * KVB];

    const int qloc = qblk * QB + wv * QW + lo32;

    const int ksr = tid >> 2;
    const int ksc = tid & 3;
    const int vd  = tid & 63;
    const int vw  = tid >> 6;

    half8 Qhi[4], Qlo[4];
    #pragma unroll
    for (int f = 0; f < 4; ++f) {
        const float* src = Qp + (size_t)qloc * D_ + f * 16 + hi * 8;
        float4 a = *(const float4*)src;
        float4 c = *(const float4*)(src + 4);
        float v8[8] = {a.x, a.y, a.z, a.w, c.x, c.y, c.z, c.w};
        half8 hh, hl;
        #pragma unroll
        for (int j = 0; j < 8; ++j) {
            _Float16 h = (_Float16)v8[j];
            hh[j] = h;
            hl[j] = (_Float16)(v8[j] - (float)h);
        }
        Qhi[f] = hh; Qlo[f] = hl;
    }

    f32x16 acc0, acc1;
    #pragma unroll
    for (int i = 0; i < 16; ++i) { acc0[i] = 0.f; acc1[i] = 0.f; }
    float mrun = -1e30f, lrun = 0.f;

    const float kScL2 = 0.125f * 1.44269504088896340736f;
    const float kL2E  = 1.44269504088896340736f;

    float4 kr[4];
    float  vr[16];
    float4 mcur[4], mnxt[4];

    auto stage_load = [&](int kv) {
        const float* ks = Kp + (size_t)(kv + ksr) * D_ + ksc * 16;
        #pragma unroll
        for (int i = 0; i < 4; ++i) kr[i] = *(const float4*)(ks + 4 * i);
        const float* vs = Vp + (size_t)(kv + vw * 16) * D_ + vd;
        #pragma unroll
        for (int r = 0; r < 16; ++r) vr[r] = vs[(size_t)r * D_];
    };
    auto stage_write = [&](int bf) {
        #pragma unroll
        for (int u = 0; u < 2; ++u) {
            float e[8] = {kr[2*u].x, kr[2*u].y, kr[2*u].z, kr[2*u].w,
                          kr[2*u+1].x, kr[2*u+1].y, kr[2*u+1].z, kr[2*u+1].w};
            half8 hh, hl;
            #pragma unroll
            for (int j = 0; j < 8; ++j) {
                _Float16 h = (_Float16)e[j];
                hh[j] = h;
                hl[j] = (_Float16)(e[j] - (float)h);
            }
            const int cs = (ksc * 2 + u) ^ (ksr & 7);
            *(half8*)&Khi[bf][ksr * 64 + cs * 8] = hh;
            *(half8*)&Klo[bf][ksr * 64 + cs * 8] = hl;
        }
        #pragma unroll
        for (int u = 0; u < 2; ++u) {
            half8 hh, hl;
            #pragma unroll
            for (int j = 0; j < 8; ++j) {
                float x = vr[8*u + j];
                _Float16 h = (_Float16)x;
                hh[j] = h;
                hl[j] = (_Float16)(x - (float)h);
            }
            const int c = (vw * 2 + u) ^ (vd & 3) ^ ((vd >> 2) & 3);
            *(half8*)&VThi[bf][vd * 32 + c * 8] = hh;
            *(half8*)&VTlo[bf][vd * 32 + c * 8] = hl;
        }
    };
    auto mask_load = [&](int kv, float4* mv) {
        const float* mrow = Mp + (size_t)qloc * S_ + kv;
        #pragma unroll
        for (int g = 0; g < 4; ++g) mv[g] = *(const float4*)(mrow + 8 * g + 4 * hi);
    };

    stage_load(0);
    stage_write(0);
    mask_load(0, mcur);
    __syncthreads();

    for (int t = 0; t < NIT; ++t) {
        const int bf = t & 1;
        if (t + 1 < NIT) {
            mask_load((t + 1) * KVB, mnxt);
            stage_load((t + 1) * KVB);
        }

        f32x16 s;
        #pragma unroll
        for (int i = 0; i < 16; ++i) s[i] = 0.f;
        #pragma unroll
        for (int f = 0; f < 4; ++f) {
            const int cs = (2 * f + hi) ^ (lo32 & 7);
            half8 ah = *(const half8*)&Khi[bf][lo32 * 64 + cs * 8];
            half8 al = *(const half8*)&Klo[bf][lo32 * 64 + cs * 8];
            s = __builtin_amdgcn_mfma_f32_32x32x16_f16(ah, Qhi[f], s, 0, 0, 0);
            s = __builtin_amdgcn_mfma_f32_32x32x16_f16(al, Qhi[f], s, 0, 0, 0);
            s = __builtin_amdgcn_mfma_f32_32x32x16_f16(ah, Qlo[f], s, 0, 0, 0);
        }

        float p[16];
        #pragma unroll
        for (int g = 0; g < 4; ++g) {
            p[4*g+0] = fmaf(s[4*g+0], kScL2, mcur[g].x * kL2E);
            p[4*g+1] = fmaf(s[4*g+1], kScL2, mcur[g].y * kL2E);
            p[4*g+2] = fmaf(s[4*g+2], kScL2, mcur[g].z * kL2E);
            p[4*g+3] = fmaf(s[4*g+3], kScL2, mcur[g].w * kL2E);
        }

        float mt = p[0];
        #pragma unroll
        for (int r = 1; r < 16; ++r) mt = fmaxf(mt, p[r]);
        mt = fmaxf(mt, __shfl_xor(mt, 32));
        const float mnew = fmaxf(mrun, mt);
        const float corr = __builtin_amdgcn_exp2f(mrun - mnew);
        float ps = 0.f;
        #pragma unroll
        for (int r = 0; r < 16; ++r) {
            p[r] = __builtin_amdgcn_exp2f(p[r] - mnew);
            ps += p[r];
        }
        ps += __shfl_xor(ps, 32);
        lrun = lrun * corr + ps;
        mrun = mnew;
        #pragma unroll
        for (int i = 0; i < 16; ++i) { acc0[i] *= corr; acc1[i] *= corr; }

        int dw[8], px[8];
        #pragma unroll
        for (int g = 0; g < 4; ++g) {
            union { fp16x2 h; int i; } u0, u1;
            u0.h = __builtin_amdgcn_cvt_pkrtz(p[4*g+0], p[4*g+1]);
            u1.h = __builtin_amdgcn_cvt_pkrtz(p[4*g+2], p[4*g+3]);
            dw[2*g]   = u0.i;
            dw[2*g+1] = u1.i;
        }
        #pragma unroll
        for (int i = 0; i < 8; ++i) px[i] = __shfl_xor(dw[i], 32);

        half8 Pf[2];
        #pragma unroll
        for (int ks = 0; ks < 2; ++ks) {
            union { int i[4]; half8 h; } f;
            f.i[0] = hi ? px[4*ks+2] : dw[4*ks+0];
            f.i[1] = hi ? px[4*ks+3] : dw[4*ks+1];
            f.i[2] = hi ? dw[4*ks+2] : px[4*ks+0];
            f.i[3] = hi ? dw[4*ks+3] : px[4*ks+1];
            Pf[ks] = f.h;
        }

        #pragma unroll
        for (int ks = 0; ks < 2; ++ks) {
            const int c0 = (2 * ks + hi) ^ (lo32 & 3) ^ ((lo32 >> 2) & 3);
            half8 vh0 = *(const half8*)&VThi[bf][lo32        * 32 + c0 * 8];
            half8 vl0 = *(const half8*)&VTlo[bf][lo32        * 32 + c0 * 8];
            half8 vh1 = *(const half8*)&VThi[bf][(32 + lo32) * 32 + c0 * 8];
            half8 vl1 = *(const half8*)&VTlo[bf][(32 + lo32) * 32 + c0 * 8];
            acc0 = __builtin_amdgcn_mfma_f32_32x32x16_f16(vh0, Pf[ks], acc0, 0, 0, 0);
            acc0 = __builtin_amdgcn_mfma_f32_32x32x16_f16(vl0, Pf[ks], acc0, 0, 0, 0);
            acc1 = __builtin_amdgcn_mfma_f32_32x32x16_f16(vh1, Pf[ks], acc1, 0, 0, 0);
            acc1 = __builtin_amdgcn_mfma_f32_32x32x16_f16(vl1, Pf[ks], acc1, 0, 0, 0);
        }

        if (t + 1 < NIT) stage_write(bf ^ 1);
        #pragma unroll
        for (int g = 0; g < 4; ++g) mcur[g] = mnxt[g];
        __syncthreads();
    }

    const float inv = 1.0f / lrun;
    #pragma unroll
    for (int r = 0; r < 16; ++r) {
        const int drow = (r & 3) + 8 * (r >> 2) + 4 * hi;
        Op[(size_t)qloc * D_ + drow]      = acc0[r] * inv;
        Op[(size_t)qloc * D_ + 32 + drow] = acc1[r] * inv;
    }
}

extern "C" void kernel_launch(void* const* d_in, const int* in_sizes, int n_in,
                              void* d_out, int out_size, void* d_ws, size_t ws_size,
                              hipStream_t stream)
{
    (void)in_sizes; (void)n_in; (void)out_size;
    const float* Q = (const float*)d_in[0];
    const float* K = (const float*)d_in[1];
    const float* V = (const float*)d_in[2];
    const float* M = (const float*)d_in[3];
    float* O = (float*)d_out;

    const size_t need = (size_t)(B_ * H_) * NIT * 8192 * sizeof(_Float16); // 33.5 MB
    if (ws_size >= need) {
        _Float16* W = (_Float16*)d_ws;
        presplit<<<dim3(NIT, B_ * H_), 256, 0, stream>>>(K, V, W);
        fattn2<<<dim3(S_ / QB, B_ * H_), 128, 0, stream>>>(Q, M, W, O);
    } else {
        fattn<<<dim3(S_ / QB, B_ * H_), 128, 0, stream>>>(Q, K, V, M, O);
    }
}

// Round 12
// 223.310 us; speedup vs baseline: 1.3747x; 1.0301x over previous
//
#include <hip/hip_runtime.h>

#define B_ 2
#define H_ 16
#define S_ 2048
#define D_ 64

typedef __attribute__((ext_vector_type(8))) _Float16 half8;
typedef __attribute__((ext_vector_type(2))) __fp16 fp16x2;
typedef __attribute__((ext_vector_type(16))) float f32x16;

constexpr int QW  = 32;        // q rows per wave (MFMA N)
constexpr int NW  = 4;         // waves per block
constexpr int QB  = QW * NW;   // 128 q rows per block
constexpr int KVB = 32;        // kv rows per tile
constexpr int NIT = S_ / KVB;  // 64 tiles

#define GLOBAL_AS(p) ((const __attribute__((address_space(1))) void*)(p))
#define LDS_AS(p)    ((__attribute__((address_space(3))) void*)(p))

// ---------------------------------------------------------------------------
// Pre-pass: split K,V into f16 hi/lo, transpose V, bake the LDS swizzle into
// the global layout so the attention kernel can global_load_lds linearly.
// Chunk layout per (bh, tile): 8192 halves = 16KB:
//   [0,2048)    Khi   [32 rows][64 cols], chunk cs = l ^ (r&7)
//   [2048,4096) Klo
//   [4096,6144) VThi  [64 d][32 k], chunk cw = c ^ (d&3) ^ ((d>>2)&3)
//   [6144,8192) VTlo
// ---------------------------------------------------------------------------
__global__ __launch_bounds__(256)
void presplit(const float* __restrict__ Kg, const float* __restrict__ Vg,
              _Float16* __restrict__ W)
{
    const int t   = blockIdx.x;    // kv tile 0..63
    const int bh  = blockIdx.y;    // 0..31
    const int tid = threadIdx.x;

    const float* Kp = Kg + (size_t)bh * S_ * D_ + (size_t)t * KVB * D_;
    const float* Vp = Vg + (size_t)bh * S_ * D_ + (size_t)t * KVB * D_;
    _Float16*    Wp = W + ((size_t)bh * NIT + t) * 8192;

    // ---- K: r = tid>>3 (row 0..31), l = tid&7 (8-col chunk)
    {
        const int r = tid >> 3, l = tid & 7;
        const float* src = Kp + r * D_ + l * 8;
        float4 a = *(const float4*)src;
        float4 c = *(const float4*)(src + 4);
        float e[8] = {a.x, a.y, a.z, a.w, c.x, c.y, c.z, c.w};
        half8 hh, hl;
        #pragma unroll
        for (int j = 0; j < 8; ++j) {
            _Float16 h = (_Float16)e[j];
            hh[j] = h;
            hl[j] = (_Float16)(e[j] - (float)h);
        }
        const int cs = l ^ (r & 7);
        *(half8*)&Wp[r * 64 + cs * 8]        = hh;
        *(half8*)&Wp[2048 + r * 64 + cs * 8] = hl;
    }
    // ---- V^T: d = tid&63 (column), c = tid>>6 (8-row chunk of k)
    {
        const int d = tid & 63, c = tid >> 6;
        float e[8];
        #pragma unroll
        for (int j = 0; j < 8; ++j) e[j] = Vp[(size_t)(c * 8 + j) * D_ + d];
        half8 hh, hl;
        #pragma unroll
        for (int j = 0; j < 8; ++j) {
            _Float16 h = (_Float16)e[j];
            hh[j] = h;
            hl[j] = (_Float16)(e[j] - (float)h);
        }
        const int cw = c ^ (d & 3) ^ ((d >> 2) & 3);
        *(half8*)&Wp[4096 + d * 32 + cw * 8] = hh;
        *(half8*)&Wp[6144 + d * 32 + cw * 8] = hl;
    }
}

// ---------------------------------------------------------------------------
// Fast attention kernel: pre-split K/V staged via global_load_lds (zero VALU)
// NW=4 waves/block -> 512 blocks, 2 blocks/CU = full 8-wave/CU residency
// ---------------------------------------------------------------------------
__global__ __launch_bounds__(256, 2)
void fattn2(const float* __restrict__ Qg, const float* __restrict__ Mg,
            const _Float16* __restrict__ W, float* __restrict__ Og)
{
    const int tid  = threadIdx.x;
    const int lane = tid & 63;
    const int lo32 = tid & 31;
    const int hi   = (tid >> 5) & 1;
    const int wv   = tid >> 6;         // 0..3

    const int qblk = blockIdx.x;       // 0..15
    const int bh   = blockIdx.y;       // 0..31
    const int b    = bh >> 4;

    const float* Qp = Qg + (size_t)bh * S_ * D_;
    const float* Mp = Mg + (size_t)b  * S_ * S_;
    float*       Op = Og + (size_t)bh * S_ * D_;
    const _Float16* Wp = W + (size_t)bh * NIT * 8192;

    // one 16KB tile per buffer: [0,2048) Khi | Klo | VThi | VTlo
    __shared__ __align__(16) _Float16 TILE[2][8192];

    const int qloc = qblk * QB + wv * QW + lo32;

    // ---- Q fragments (B-operand), hi/lo split
    half8 Qhi[4], Qlo[4];
    #pragma unroll
    for (int f = 0; f < 4; ++f) {
        const float* src = Qp + (size_t)qloc * D_ + f * 16 + hi * 8;
        float4 a = *(const float4*)src;
        float4 c = *(const float4*)(src + 4);
        float v8[8] = {a.x, a.y, a.z, a.w, c.x, c.y, c.z, c.w};
        half8 hh, hl;
        #pragma unroll
        for (int j = 0; j < 8; ++j) {
            _Float16 h = (_Float16)v8[j];
            hh[j] = h;
            hl[j] = (_Float16)(v8[j] - (float)h);
        }
        Qhi[f] = hh; Qlo[f] = hl;
    }

    f32x16 acc0, acc1;
    #pragma unroll
    for (int i = 0; i < 16; ++i) { acc0[i] = 0.f; acc1[i] = 0.f; }
    float mrun = -1e30f, lrun = 0.f;

    const float kScL2 = 0.125f * 1.44269504088896340736f;
    const float kL2E  = 1.44269504088896340736f;

    float4 mcur[4], mnxt[4];

    // wave wv stages halves [wv*2048, wv*2048+2048): 4 x 1KB global_load_lds
    auto stage = [&](int bf, int t) {
        const _Float16* src = Wp + (size_t)t * 8192 + wv * 2048 + lane * 8;
        _Float16* dst = &TILE[bf][wv * 2048];
        #pragma unroll
        for (int c = 0; c < 4; ++c)
            __builtin_amdgcn_global_load_lds(GLOBAL_AS(src + c * 512),
                                             LDS_AS(dst + c * 512), 16, 0, 0);
    };
    auto mask_load = [&](int kv, float4* mv) {
        const float* mrow = Mp + (size_t)qloc * S_ + kv;
        #pragma unroll
        for (int g = 0; g < 4; ++g) mv[g] = *(const float4*)(mrow + 8 * g + 4 * hi);
    };

    stage(0, 0);
    mask_load(0, mcur);
    __syncthreads();

    for (int t = 0; t < NIT; ++t) {
        const int bf = t & 1;
        if (t + 1 < NIT) {
            mask_load((t + 1) * KVB, mnxt);
            stage(bf ^ 1, t + 1);         // prefetch; drained by end-of-iter barrier
        }

        // ---------- S^T = K · Q^T  (3-term hi/lo split)
        f32x16 s;
        #pragma unroll
        for (int i = 0; i < 16; ++i) s[i] = 0.f;
        __builtin_amdgcn_s_setprio(1);
        #pragma unroll
        for (int f = 0; f < 4; ++f) {
            const int cs = (2 * f + hi) ^ (lo32 & 7);
            half8 ah = *(const half8*)&TILE[bf][lo32 * 64 + cs * 8];
            half8 al = *(const half8*)&TILE[bf][2048 + lo32 * 64 + cs * 8];
            s = __builtin_amdgcn_mfma_f32_32x32x16_f16(ah, Qhi[f], s, 0, 0, 0);
            s = __builtin_amdgcn_mfma_f32_32x32x16_f16(al, Qhi[f], s, 0, 0, 0);
            s = __builtin_amdgcn_mfma_f32_32x32x16_f16(ah, Qlo[f], s, 0, 0, 0);
        }
        __builtin_amdgcn_s_setprio(0);

        // ---------- scale + mask (base-2 log domain)
        float p[16];
        #pragma unroll
        for (int g = 0; g < 4; ++g) {
            p[4*g+0] = fmaf(s[4*g+0], kScL2, mcur[g].x * kL2E);
            p[4*g+1] = fmaf(s[4*g+1], kScL2, mcur[g].y * kL2E);
            p[4*g+2] = fmaf(s[4*g+2], kScL2, mcur[g].z * kL2E);
            p[4*g+3] = fmaf(s[4*g+3], kScL2, mcur[g].w * kL2E);
        }

        // ---------- online softmax + T13 defer-max (P bounded by 2^8)
        float mt = p[0];
        #pragma unroll
        for (int r = 1; r < 16; ++r) mt = fmaxf(mt, p[r]);
        mt = fmaxf(mt, __shfl_xor(mt, 32));
        if (!__all(mt - mrun <= 8.0f)) {
            const float mnew = fmaxf(mrun, mt);
            const float corr = __builtin_amdgcn_exp2f(mrun - mnew);
            lrun *= corr;
            #pragma unroll
            for (int i = 0; i < 16; ++i) { acc0[i] *= corr; acc1[i] *= corr; }
            mrun = mnew;
        }
        float ps = 0.f;
        #pragma unroll
        for (int r = 0; r < 16; ++r) {
            p[r] = __builtin_amdgcn_exp2f(p[r] - mrun);
            ps += p[r];
        }
        ps += __shfl_xor(ps, 32);
        lrun += ps;

        // ---------- pack P to f16 and build B-operand frags
        int dw[8], px[8];
        #pragma unroll
        for (int g = 0; g < 4; ++g) {
            union { fp16x2 h; int i; } u0, u1;
            u0.h = __builtin_amdgcn_cvt_pkrtz(p[4*g+0], p[4*g+1]);
            u1.h = __builtin_amdgcn_cvt_pkrtz(p[4*g+2], p[4*g+3]);
            dw[2*g]   = u0.i;
            dw[2*g+1] = u1.i;
        }
        #pragma unroll
        for (int i = 0; i < 8; ++i) px[i] = __shfl_xor(dw[i], 32);

        half8 Pf[2];
        #pragma unroll
        for (int ks = 0; ks < 2; ++ks) {
            union { int i[4]; half8 h; } f;
            f.i[0] = hi ? px[4*ks+2] : dw[4*ks+0];
            f.i[1] = hi ? px[4*ks+3] : dw[4*ks+1];
            f.i[2] = hi ? dw[4*ks+2] : px[4*ks+0];
            f.i[3] = hi ? dw[4*ks+3] : px[4*ks+1];
            Pf[ks] = f.h;
        }

        // ---------- O^T += V^T · P   (V hi/lo split)
        __builtin_amdgcn_s_setprio(1);
        #pragma unroll
        for (int ks = 0; ks < 2; ++ks) {
            const int c0 = (2 * ks + hi) ^ (lo32 & 3) ^ ((lo32 >> 2) & 3);
            half8 vh0 = *(const half8*)&TILE[bf][4096 + lo32        * 32 + c0 * 8];
            half8 vl0 = *(const half8*)&TILE[bf][6144 + lo32        * 32 + c0 * 8];
            half8 vh1 = *(const half8*)&TILE[bf][4096 + (32 + lo32) * 32 + c0 * 8];
            half8 vl1 = *(const half8*)&TILE[bf][6144 + (32 + lo32) * 32 + c0 * 8];
            acc0 = __builtin_amdgcn_mfma_f32_32x32x16_f16(vh0, Pf[ks], acc0, 0, 0, 0);
            acc0 = __builtin_amdgcn_mfma_f32_32x32x16_f16(vl0, Pf[ks], acc0, 0, 0, 0);
            acc1 = __builtin_amdgcn_mfma_f32_32x32x16_f16(vh1, Pf[ks], acc1, 0, 0, 0);
            acc1 = __builtin_amdgcn_mfma_f32_32x32x16_f16(vl1, Pf[ks], acc1, 0, 0, 0);
        }
        __builtin_amdgcn_s_setprio(0);

        #pragma unroll
        for (int g = 0; g < 4; ++g) mcur[g] = mnxt[g];
        __syncthreads();   // drains prefetch vmcnt + flips buffers
    }

    const float inv = 1.0f / lrun;
    #pragma unroll
    for (int r = 0; r < 16; ++r) {
        const int drow = (r & 3) + 8 * (r >> 2) + 4 * hi;
        Op[(size_t)qloc * D_ + drow]      = acc0[r] * inv;
        Op[(size_t)qloc * D_ + 32 + drow] = acc1[r] * inv;
    }
}

// ---------------------------------------------------------------------------
// Fallback (R4 kernel, verified PASS @ ~170us): used when ws_size is too small
// ---------------------------------------------------------------------------
__global__ __launch_bounds__(128, 2)
void fattn(const float* __restrict__ Qg, const float* __restrict__ Kg,
           const float* __restrict__ Vg, const float* __restrict__ Mg,
           float* __restrict__ Og)
{
    const int tid  = threadIdx.x;
    const int lo32 = tid & 31;
    const int hi   = (tid >> 5) & 1;
    const int wv   = tid >> 6;

    const int qblk = blockIdx.x;
    const int bh   = blockIdx.y;
    const int b    = bh >> 4;

    const float* Qp = Qg + (size_t)bh * S_ * D_;
    const float* Kp = Kg + (size_t)bh * S_ * D_;
    const float* Vp = Vg + (size_t)bh * S_ * D_;
    const float* Mp = Mg + (size_t)b  * S_ * S_;
    float*       Op = Og + (size_t)bh * S_ * D_;

    __shared__ __align__(16) _Float16 Khi[2][KVB * D_];
    __shared__ __align__(16) _Float16 Klo[2][KVB * D_];
    __shared__ __align__(16) _Float16 VThi[2][D_ * KVB];
    __shared__ __align__(16) _Float16 VTlo[2][D_ * KVB];

    const int qloc = qblk * 64 + wv * QW + lo32;

    const int ksr = tid >> 2;
    const int ksc = tid & 3;
    const int vd  = tid & 63;
    const int vw  = tid >> 6;

    half8 Qhi[4], Qlo[4];
    #pragma unroll
    for (int f = 0; f < 4; ++f) {
        const float* src = Qp + (size_t)qloc * D_ + f * 16 + hi * 8;
        float4 a = *(const float4*)src;
        float4 c = *(const float4*)(src + 4);
        float v8[8] = {a.x, a.y, a.z, a.w, c.x, c.y, c.z, c.w};
        half8 hh, hl;
        #pragma unroll
        for (int j = 0; j < 8; ++j) {
            _Float16 h = (_Float16)v8[j];
            hh[j] = h;
            hl[j] = (_Float16)(v8[j] - (float)h);
        }
        Qhi[f] = hh; Qlo[f] = hl;
    }

    f32x16 acc0, acc1;
    #pragma unroll
    for (int i = 0; i < 16; ++i) { acc0[i] = 0.f; acc1[i] = 0.f; }
    float mrun = -1e30f, lrun = 0.f;

    const float kScL2 = 0.125f * 1.44269504088896340736f;
    const float kL2E  = 1.44269504088896340736f;

    float4 kr[4];
    float  vr[16];
    float4 mcur[4], mnxt[4];

    auto stage_load = [&](int kv) {
        const float* ks = Kp + (size_t)(kv + ksr) * D_ + ksc * 16;
        #pragma unroll
        for (int i = 0; i < 4; ++i) kr[i] = *(const float4*)(ks + 4 * i);
        const float* vs = Vp + (size_t)(kv + vw * 16) * D_ + vd;
        #pragma unroll
        for (int r = 0; r < 16; ++r) vr[r] = vs[(size_t)r * D_];
    };
    auto stage_write = [&](int bf) {
        #pragma unroll
        for (int u = 0; u < 2; ++u) {
            float e[8] = {kr[2*u].x, kr[2*u].y, kr[2*u].z, kr[2*u].w,
                          kr[2*u+1].x, kr[2*u+1].y, kr[2*u+1].z, kr[2*u+1].w};
            half8 hh, hl;
            #pragma unroll
            for (int j = 0; j < 8; ++j) {
                _Float16 h = (_Float16)e[j];
                hh[j] = h;
                hl[j] = (_Float16)(e[j] - (float)h);
            }
            const int cs = (ksc * 2 + u) ^ (ksr & 7);
            *(half8*)&Khi[bf][ksr * 64 + cs * 8] = hh;
            *(half8*)&Klo[bf][ksr * 64 + cs * 8] = hl;
        }
        #pragma unroll
        for (int u = 0; u < 2; ++u) {
            half8 hh, hl;
            #pragma unroll
            for (int j = 0; j < 8; ++j) {
                float x = vr[8*u + j];
                _Float16 h = (_Float16)x;
                hh[j] = h;
                hl[j] = (_Float16)(x - (float)h);
            }
            const int c = (vw * 2 + u) ^ (vd & 3) ^ ((vd >> 2) & 3);
            *(half8*)&VThi[bf][vd * 32 + c * 8] = hh;
            *(half8*)&VTlo[bf][vd * 32 + c * 8] = hl;
        }
    };
    auto mask_load = [&](int kv, float4* mv) {
        const float* mrow = Mp + (size_t)qloc * S_ + kv;
        #pragma unroll
        for (int g = 0; g < 4; ++g) mv[g] = *(const float4*)(mrow + 8 * g + 4 * hi);
    };

    stage_load(0);
    stage_write(0);
    mask_load(0, mcur);
    __syncthreads();

    for (int t = 0; t < NIT; ++t) {
        const int bf = t & 1;
        if (t + 1 < NIT) {
            mask_load((t + 1) * KVB, mnxt);
            stage_load((t + 1) * KVB);
        }

        f32x16 s;
        #pragma unroll
        for (int i = 0; i < 16; ++i) s[i] = 0.f;
        #pragma unroll
        for (int f = 0; f < 4; ++f) {
            const int cs = (2 * f + hi) ^ (lo32 & 7);
            half8 ah = *(const half8*)&Khi[bf][lo32 * 64 + cs * 8];
            half8 al = *(const half8*)&Klo[bf][lo32 * 64 + cs * 8];
            s = __builtin_amdgcn_mfma_f32_32x32x16_f16(ah, Qhi[f], s, 0, 0, 0);
            s = __builtin_amdgcn_mfma_f32_32x32x16_f16(al, Qhi[f], s, 0, 0, 0);
            s = __builtin_amdgcn_mfma_f32_32x32x16_f16(ah, Qlo[f], s, 0, 0, 0);
        }

        float p[16];
        #pragma unroll
        for (int g = 0; g < 4; ++g) {
            p[4*g+0] = fmaf(s[4*g+0], kScL2, mcur[g].x * kL2E);
            p[4*g+1] = fmaf(s[4*g+1], kScL2, mcur[g].y * kL2E);
            p[4*g+2] = fmaf(s[4*g+2], kScL2, mcur[g].z * kL2E);
            p[4*g+3] = fmaf(s[4*g+3], kScL2, mcur[g].w * kL2E);
        }

        float mt = p[0];
        #pragma unroll
        for (int r = 1; r < 16; ++r) mt = fmaxf(mt, p[r]);
        mt = fmaxf(mt, __shfl_xor(mt, 32));
        const float mnew = fmaxf(mrun, mt);
        const float corr = __builtin_amdgcn_exp2f(mrun - mnew);
        float ps = 0.f;
        #pragma unroll
        for (int r = 0; r < 16; ++r) {
            p[r] = __builtin_amdgcn_exp2f(p[r] - mnew);
            ps += p[r];
        }
        ps += __shfl_xor(ps, 32);
        lrun = lrun * corr + ps;
        mrun = mnew;
        #pragma unroll
        for (int i = 0; i < 16; ++i) { acc0[i] *= corr; acc1[i] *= corr; }

        int dw[8], px[8];
        #pragma unroll
        for (int g = 0; g < 4; ++g) {
            union { fp16x2 h; int i; } u0, u1;
            u0.h = __builtin_amdgcn_cvt_pkrtz(p[4*g+0], p[4*g+1]);
            u1.h = __builtin_amdgcn_cvt_pkrtz(p[4*g+2], p[4*g+3]);
            dw[2*g]   = u0.i;
            dw[2*g+1] = u1.i;
        }
        #pragma unroll
        for (int i = 0; i < 8; ++i) px[i] = __shfl_xor(dw[i], 32);

        half8 Pf[2];
        #pragma unroll
        for (int ks = 0; ks < 2; ++ks) {
            union { int i[4]; half8 h; } f;
            f.i[0] = hi ? px[4*ks+2] : dw[4*ks+0];
            f.i[1] = hi ? px[4*ks+3] : dw[4*ks+1];
            f.i[2] = hi ? dw[4*ks+2] : px[4*ks+0];
            f.i[3] = hi ? dw[4*ks+3] : px[4*ks+1];
            Pf[ks] = f.h;
        }

        #pragma unroll
        for (int ks = 0; ks < 2; ++ks) {
            const int c0 = (2 * ks + hi) ^ (lo32 & 3) ^ ((lo32 >> 2) & 3);
            half8 vh0 = *(const half8*)&VThi[bf][lo32        * 32 + c0 * 8];
            half8 vl0 = *(const half8*)&VTlo[bf][lo32        * 32 + c0 * 8];
            half8 vh1 = *(const half8*)&VThi[bf][(32 + lo32) * 32 + c0 * 8];
            half8 vl1 = *(const half8*)&VTlo[bf][(32 + lo32) * 32 + c0 * 8];
            acc0 = __builtin_amdgcn_mfma_f32_32x32x16_f16(vh0, Pf[ks], acc0, 0, 0, 0);
            acc0 = __builtin_amdgcn_mfma_f32_32x32x16_f16(vl0, Pf[ks], acc0, 0, 0, 0);
            acc1 = __builtin_amdgcn_mfma_f32_32x32x16_f16(vh1, Pf[ks], acc1, 0, 0, 0);
            acc1 = __builtin_amdgcn_mfma_f32_32x32x16_f16(vl1, Pf[ks], acc1, 0, 0, 0);
        }

        if (t + 1 < NIT) stage_write(bf ^ 1);
        #pragma unroll
        for (int g = 0; g < 4; ++g) mcur[g] = mnxt[g];
        __syncthreads();
    }

    const float inv = 1.0f / lrun;
    #pragma unroll
    for (int r = 0; r < 16; ++r) {
        const int drow = (r & 3) + 8 * (r >> 2) + 4 * hi;
        Op[(size_t)qloc * D_ + drow]      = acc0[r] * inv;
        Op[(size_t)qloc * D_ + 32 + drow] = acc1[r] * inv;
    }
}

extern "C" void kernel_launch(void* const* d_in, const int* in_sizes, int n_in,
                              void* d_out, int out_size, void* d_ws, size_t ws_size,
                              hipStream_t stream)
{
    (void)in_sizes; (void)n_in; (void)out_size;
    const float* Q = (const float*)d_in[0];
    const float* K = (const float*)d_in[1];
    const float* V = (const float*)d_in[2];
    const float* M = (const float*)d_in[3];
    float* O = (float*)d_out;

    const size_t need = (size_t)(B_ * H_) * NIT * 8192 * sizeof(_Float16); // 33.5 MB
    if (ws_size >= need) {
        _Float16* W = (_Float16*)d_ws;
        presplit<<<dim3(NIT, B_ * H_), 256, 0, stream>>>(K, V, W);
        fattn2<<<dim3(S_ / QB, B_ * H_), 256, 0, stream>>>(Q, M, W, O);
    } else {
        fattn<<<dim3(S_ / 64, B_ * H_), 128, 0, stream>>>(Q, K, V, M, O);
    }
}